// Round 13
// baseline (353.247 us; speedup 1.0000x reference)
//
#include <hip/hip_runtime.h>

typedef __attribute__((ext_vector_type(8))) __bf16 bf16x8;
typedef __attribute__((ext_vector_type(4))) float f32x4;
typedef __attribute__((ext_vector_type(8))) unsigned short u16x8;
typedef __attribute__((ext_vector_type(4))) unsigned short u16x4;
typedef unsigned int u32;

#define KS2 32   // gemm2 split-K factor

// f32 -> bf16 bits, round-to-nearest-even
__device__ __forceinline__ unsigned short f2b(float f) {
    union { float f; unsigned u; } v; v.f = f;
    unsigned r = v.u + 0x7fffu + ((v.u >> 16) & 1u);
    return (unsigned short)(r >> 16);
}

// bf16 bits -> f32
__device__ __forceinline__ float b2f(unsigned short b) {
    union { unsigned u; float f; } v; v.u = ((unsigned)b) << 16;
    return v.f;
}

__device__ __forceinline__ bf16x8 ld_frag(const unsigned short* p) {
    u16x8 v = *(const u16x8*)p;
    return __builtin_bit_cast(bf16x8, v);
}

// async 16B global -> LDS (linear dest: wave base + lane*16)
__device__ __forceinline__ void gl16(void* lds, const void* g) {
    __builtin_amdgcn_global_load_lds(
        (const __attribute__((address_space(1))) u32*)g,
        (__attribute__((address_space(3))) u32*)lds, 16, 0, 0);
}

#define WAIT_VM0 asm volatile("s_waitcnt vmcnt(0)" ::: "memory")
#define WAIT_VM3 asm volatile("s_waitcnt vmcnt(3)" ::: "memory")
#define WAIT_VM4 asm volatile("s_waitcnt vmcnt(4)" ::: "memory")
#define WAIT_VM6 asm volatile("s_waitcnt vmcnt(6)" ::: "memory")
#define WAIT_VM8 asm volatile("s_waitcnt vmcnt(8)" ::: "memory")
#define WAIT_LG0 asm volatile("s_waitcnt lgkmcnt(0)" ::: "memory")
#define BARRIER  __builtin_amdgcn_s_barrier()

// params-column permutation: pm col j holds original param index inv(j)
__device__ __forceinline__ int inv_col(int j) {
    int off = j & 8191;
    return (off < 4096) ? ((j & ~8191) | ((off & 63) << 6) | (off >> 6)) : j;
}

// block-wide sum of s and q across 256 threads (4 waves), deterministic
__device__ __forceinline__ void block_reduce2(float& s, float& q, float* red) {
    for (int m = 1; m < 64; m <<= 1) { s += __shfl_xor(s, m); q += __shfl_xor(q, m); }
    int w = threadIdx.x >> 6;
    __syncthreads();
    if ((threadIdx.x & 63) == 0) { red[w] = s; red[w + 4] = q; }
    __syncthreads();
    s = red[0] + red[1] + red[2] + red[3];
    q = red[4] + red[5] + red[6] + red[7];
}

// ---------------- conversion kernels -----------------------------------------------
__global__ __launch_bounds__(256) void k_cvt(const float* __restrict__ src,
                                             unsigned short* __restrict__ dst, int n4) {
    int i = blockIdx.x * 256 + threadIdx.x;
    int stride = gridDim.x * 256;
    for (; i < n4; i += stride) {
        f32x4 v = *(const f32x4*)&src[(size_t)i * 4];
        u16x4 o = { f2b(v[0]), f2b(v[1]), f2b(v[2]), f2b(v[3]) };
        *(u16x4*)&dst[(size_t)i * 4] = o;
    }
}

__global__ __launch_bounds__(256) void k_cvt_wp(const float* __restrict__ Wp,
                                                unsigned short* __restrict__ Wpb, int n4) {
    int i = blockIdx.x * 256 + threadIdx.x;
    int stride = gridDim.x * 256;
    for (; i < n4; i += stride) {
        int e = i * 4;
        int j = e >> 8, k = e & 255;
        int jo = inv_col(j);
        f32x4 v = *(const f32x4*)&Wp[(size_t)jo * 256 + k];
        u16x4 o = { f2b(v[0]), f2b(v[1]), f2b(v[2]), f2b(v[3]) };
        *(u16x4*)&Wpb[(size_t)e] = o;
    }
}

__global__ __launch_bounds__(256) void k_perm_bp(const float* __restrict__ bp,
                                                 float* __restrict__ bpp) {
    int j = blockIdx.x * 256 + threadIdx.x;
    bpp[j] = bp[inv_col(j)];
}

// LDS slot swizzle: physical slot p of row r holds global slot p ^ (r & 3).
// Stager: source slot = (t&3) ^ (r0&3). Reader: physical slot = k8 ^ (row&3).

// ---------------- GEMM1: pm[CH,32768] = qb @ Wpb^T + bpp (bf16 out) ----------------
// BM=256, BN=128, BK=32, 8 waves (4m x 2n). 3-buffer 2-deep counted-vmcnt pipeline.
__global__ __launch_bounds__(512) void k_gemm1(
    const unsigned short* __restrict__ qb, const unsigned short* __restrict__ Wpb,
    const float* __restrict__ bpp, unsigned short* __restrict__ pm, int CH)
{
    __shared__ char SB[73728];   // 3 bufs x 24K; epilogue Ep (64K) aliases front
    const int t = threadIdx.x, lane = t & 63, w = t >> 6;
    const int l15 = lane & 15, k8 = lane >> 4;
    const int n0 = blockIdx.x * 128, m0 = blockIdx.y * 256;
    const int wm = (w >> 1) * 64, wn = (w & 1) * 64;

    f32x4 acc[4][4];
    for (int i = 0; i < 4; ++i)
        for (int j = 0; j < 4; ++j) acc[i][j] = (f32x4){0.f, 0.f, 0.f, 0.f};

    const int r0 = t >> 2;
    const int cbs = (((t & 3) ^ (r0 & 3)) * 16);   // swizzled source slot
    int ma0 = m0 + r0;        if (ma0 > CH - 1) ma0 = CH - 1;
    int ma1 = m0 + r0 + 128;  if (ma1 > CH - 1) ma1 = CH - 1;
    const char* pa0 = (const char*)qb  + (size_t)ma0 * 512 + cbs;
    const char* pa1 = (const char*)qb  + (size_t)ma1 * 512 + cbs;
    const char* pb0 = (const char*)Wpb + (size_t)(n0 + r0) * 512 + cbs;

    char* cur = SB;
    char* nx1 = SB + 24576;
    char* nx2 = SB + 49152;

    // prologue: issue T0, T1
    gl16(cur + t * 16,         pa0);
    gl16(cur + 8192 + t * 16,  pa1);
    gl16(cur + 16384 + t * 16, pb0);
    gl16(nx1 + t * 16,         pa0 + 64);
    gl16(nx1 + 8192 + t * 16,  pa1 + 64);
    gl16(nx1 + 16384 + t * 16, pb0 + 64);

    for (int kt = 0; kt < 8; ++kt) {
        if (kt < 6) {
            const int kb = (kt + 2) * 64;
            gl16(nx2 + t * 16,         pa0 + kb);
            gl16(nx2 + 8192 + t * 16,  pa1 + kb);
            gl16(nx2 + 16384 + t * 16, pb0 + kb);
            WAIT_VM6;            // T(kt)'s 3 loads retired; 6 in flight
        } else if (kt == 6) {
            WAIT_VM3;
        } else {
            WAIT_VM0;
        }
        BARRIER;
        const unsigned short* Ab = (const unsigned short*)cur;
        const unsigned short* Bb = (const unsigned short*)(cur + 16384);
        bf16x8 a[4], b[4];
        for (int mi = 0; mi < 4; ++mi) {
            int row = wm + mi * 16 + l15;
            a[mi] = ld_frag(&Ab[row * 32 + (k8 ^ (row & 3)) * 8]);
        }
        for (int ni = 0; ni < 4; ++ni) {
            int row = wn + ni * 16 + l15;
            b[ni] = ld_frag(&Bb[row * 32 + (k8 ^ (row & 3)) * 8]);
        }
        WAIT_LG0;
        for (int mi = 0; mi < 4; ++mi)
            for (int ni = 0; ni < 4; ++ni)
                acc[mi][ni] = __builtin_amdgcn_mfma_f32_16x16x32_bf16(a[mi], b[ni], acc[mi][ni], 0, 0, 0);
        BARRIER;                 // reads of cur done before T(kt+3) overwrites it
        char* tmp = cur; cur = nx1; nx1 = nx2; nx2 = tmp;
    }

    // epilogue: bias + pack into Ep (aliases staging bufs; safe after final barrier)
    unsigned short* Ep = (unsigned short*)SB;
    for (int ni = 0; ni < 4; ++ni) {
        int col = wn + ni * 16 + l15;
        float bpv = bpp[n0 + col];
        for (int mi = 0; mi < 4; ++mi)
            for (int r = 0; r < 4; ++r) {
                int row = wm + mi * 16 + k8 * 4 + r;
                Ep[row * 128 + col] = f2b(acc[mi][ni][r] + bpv);
            }
    }
    __syncthreads();
    for (int i = 0; i < 8; ++i) {
        int off = t * 16 + i * 8192;
        int row = off >> 8, colb = off & 255;
        int cm = m0 + row;
        if (cm < CH)
            *(u16x8*)((char*)pm + (size_t)cm * 65536 + (size_t)n0 * 2 + colb) =
                *(const u16x8*)((const char*)SB + off);
    }
}

// ---------------- MIX: per (g, nq) block; in-place params->mid ---------------------
__global__ __launch_bounds__(256) void k_mix(
    const float* __restrict__ x, unsigned short* __restrict__ pm, int q0)
{
    __shared__ char SB[29184];      // MtP | Ax | Ss | O1 ; O2 aliases front 16KB
    __shared__ float red[8];
    unsigned short* MtP = (unsigned short*)SB;             // [64][72]  M^T
    unsigned short* Ax  = (unsigned short*)(SB + 9216);    // [32][72]
    unsigned short* Ss  = (unsigned short*)(SB + 13824);   // [128][40]
    unsigned short* O1  = (unsigned short*)(SB + 24064);   // [64][40]  out1^T
    unsigned short* O2  = (unsigned short*)SB;             // [128][64] final, aliased
    const int t = threadIdx.x, lane = t & 63, w = t >> 6;
    const int l15 = lane & 15, k8 = lane >> 4;
    const int g = blockIdx.x, nq = blockIdx.y;
    unsigned short* pmq = pm + (size_t)nq * 32768 + g * 8192;
    const float* xg = x + ((size_t)(q0 + nq) * 4 + g) * 2048;

    { // stage M^T (already transposed by Wp permutation)
        int d = t >> 2, c0 = (t & 3) * 16;
        u16x8 v0 = *(const u16x8*)&pmq[d * 64 + c0];
        u16x8 v1 = *(const u16x8*)&pmq[d * 64 + c0 + 8];
        *(u16x8*)&MtP[d * 72 + c0] = v0;
        *(u16x8*)&MtP[d * 72 + c0 + 8] = v1;
    }
    { // stage S
        int o = t >> 1, p0 = (t & 1) * 16;
        u16x8 v0 = *(const u16x8*)&pmq[4096 + o * 32 + p0];
        u16x8 v1 = *(const u16x8*)&pmq[4096 + o * 32 + p0 + 8];
        *(u16x8*)&Ss[o * 40 + p0] = v0;
        *(u16x8*)&Ss[o * 40 + p0 + 8] = v1;
    }
    { // stage x (f32 -> bf16)
        int p = t >> 3, c0 = (t & 7) * 8;
        f32x4 v0 = *(const f32x4*)&xg[p * 64 + c0];
        f32x4 v1 = *(const f32x4*)&xg[p * 64 + c0 + 4];
        u16x8 o8 = { f2b(v0[0]), f2b(v0[1]), f2b(v0[2]), f2b(v0[3]),
                     f2b(v1[0]), f2b(v1[1]), f2b(v1[2]), f2b(v1[3]) };
        *(u16x8*)&Ax[p * 72 + c0] = o8;
    }
    __syncthreads();

    // out1 = x @ M : 32x64, K=64. Wave w owns cols 16w..16w+15.
    f32x4 acc1[2] = { (f32x4){0.f,0.f,0.f,0.f}, (f32x4){0.f,0.f,0.f,0.f} };
    for (int kk = 0; kk < 2; ++kk) {
        bf16x8 b = ld_frag(&MtP[(16 * w + l15) * 72 + kk * 32 + k8 * 8]);
        for (int mi = 0; mi < 2; ++mi) {
            bf16x8 a = ld_frag(&Ax[(mi * 16 + l15) * 72 + kk * 32 + k8 * 8]);
            acc1[mi] = __builtin_amdgcn_mfma_f32_16x16x32_bf16(a, b, acc1[mi], 0, 0, 0);
        }
    }
    float s = 0.f, sq = 0.f;
    for (int mi = 0; mi < 2; ++mi)
        for (int r = 0; r < 4; ++r) { float v = acc1[mi][r]; s += v; sq += v * v; }
    block_reduce2(s, sq, red);
    float mean = s * (1.f / 2048.f);
    float inv = rsqrtf(sq * (1.f / 2048.f) - mean * mean + 1e-5f);
    for (int mi = 0; mi < 2; ++mi)
        for (int r = 0; r < 4; ++r) {
            float v = (acc1[mi][r] - mean) * inv; v = fmaxf(v, 0.f);
            int p = mi * 16 + k8 * 4 + r, d = 16 * w + l15;
            O1[d * 40 + p] = f2b(v);
        }
    __syncthreads();

    // out2 = S @ out1 : 128x64, K=32
    f32x4 acc2[8];
    for (int mi = 0; mi < 8; ++mi) acc2[mi] = (f32x4){0.f, 0.f, 0.f, 0.f};
    bf16x8 b2 = ld_frag(&O1[(16 * w + l15) * 40 + k8 * 8]);
    for (int mi = 0; mi < 8; ++mi) {
        bf16x8 a2 = ld_frag(&Ss[(mi * 16 + l15) * 40 + k8 * 8]);
        acc2[mi] = __builtin_amdgcn_mfma_f32_16x16x32_bf16(a2, b2, acc2[mi], 0, 0, 0);
    }
    s = 0.f; sq = 0.f;
    for (int mi = 0; mi < 8; ++mi)
        for (int r = 0; r < 4; ++r) { float v = acc2[mi][r]; s += v; sq += v * v; }
    block_reduce2(s, sq, red);   // contains barriers -> safe to alias O2 after
    mean = s * (1.f / 8192.f);
    inv = rsqrtf(sq * (1.f / 8192.f) - mean * mean + 1e-5f);
    for (int mi = 0; mi < 8; ++mi)
        for (int r = 0; r < 4; ++r) {
            float v = (acc2[mi][r] - mean) * inv; v = fmaxf(v, 0.f);
            int o = mi * 16 + k8 * 4 + r, d = 16 * w + l15;
            O2[o * 64 + d] = f2b(v);
        }
    __syncthreads();
    // coalesced write-back: 16KB contiguous
    for (int i = 0; i < 4; ++i) {
        int off = t * 16 + i * 4096;
        *(u16x8*)((char*)pmq + off) = *(const u16x8*)((const char*)O2 + off);
    }
}

// ---------------- GEMM2: part[ks,CH,256] = pm @ Wob^T (split-K KS2, bf16 part) -----
// BM=256, BN=256, BK=32, 8 waves (2m x 4n), per-wave 128x64. 3-buffer 2-deep
// pipeline. ks->XCD swizzle (R8-validated): 8 m-blocks of a ks share one XCD ->
// its 512KB Wob slice is L2-resident, fetched from L3 ~once per ks.
__global__ __launch_bounds__(512) void k_gemm2(
    const unsigned short* __restrict__ pm, const unsigned short* __restrict__ Wob,
    unsigned short* __restrict__ part, int CH, int MB2)
{
    __shared__ char SB[98304];   // 3 bufs x (A 16K | B 16K)
    const int t = threadIdx.x, lane = t & 63, w = t >> 6;
    const int l15 = lane & 15, k8 = lane >> 4;
    // swizzle: grid = KS2*MB2 (multiple of 8). xcd = bid&7; same-ks -> same XCD.
    const int bid = blockIdx.x;
    const int xcd = bid & 7, local = bid >> 3;
    const int ks = xcd + 8 * (local / MB2);
    const int m0 = (local % MB2) * 256;
    const int ksb = ks * (65536 / KS2);   // 2048 bytes (1024 elems)
    const int wm = (w >> 2) * 128, wn = (w & 3) * 64;

    f32x4 acc[8][4];
    for (int i = 0; i < 8; ++i)
        for (int j = 0; j < 4; ++j) acc[i][j] = (f32x4){0.f, 0.f, 0.f, 0.f};

    const int r0 = t >> 2;
    const int cbs = (((t & 3) ^ (r0 & 3)) * 16);   // swizzled source slot
    int ma0 = m0 + r0;        if (ma0 > CH - 1) ma0 = CH - 1;
    int ma1 = m0 + r0 + 128;  if (ma1 > CH - 1) ma1 = CH - 1;
    const char* pa0 = (const char*)pm  + (size_t)ma0 * 65536 + ksb + cbs;
    const char* pa1 = (const char*)pm  + (size_t)ma1 * 65536 + ksb + cbs;
    const char* pb0 = (const char*)Wob + (size_t)r0 * 65536 + ksb + cbs;
    const char* pb1 = pb0 + (size_t)128 * 65536;

    char* cur = SB;
    char* nx1 = SB + 32768;
    char* nx2 = SB + 65536;

    // prologue: issue T0, T1 (4 loads each)
    gl16(cur + t * 16,          pa0);
    gl16(cur + 8192 + t * 16,   pa1);
    gl16(cur + 16384 + t * 16,  pb0);
    gl16(cur + 24576 + t * 16,  pb1);
    gl16(nx1 + t * 16,          pa0 + 64);
    gl16(nx1 + 8192 + t * 16,   pa1 + 64);
    gl16(nx1 + 16384 + t * 16,  pb0 + 64);
    gl16(nx1 + 24576 + t * 16,  pb1 + 64);

    const int NT = (65536 / KS2) / 64;   // 32 K-steps
    for (int kt = 0; kt < NT; ++kt) {
        if (kt < NT - 2) {
            const int kb = (kt + 2) * 64;
            gl16(nx2 + t * 16,          pa0 + kb);
            gl16(nx2 + 8192 + t * 16,   pa1 + kb);
            gl16(nx2 + 16384 + t * 16,  pb0 + kb);
            gl16(nx2 + 24576 + t * 16,  pb1 + kb);
            WAIT_VM8;            // T(kt)'s 4 loads retired; 8 in flight
        } else if (kt == NT - 2) {
            WAIT_VM4;
        } else {
            WAIT_VM0;
        }
        BARRIER;
        const unsigned short* Ab = (const unsigned short*)cur;          // rows 0..255
        const unsigned short* Bb = (const unsigned short*)(cur + 16384); // rows 0..255
        bf16x8 a[8], b[4];
        for (int mi = 0; mi < 8; ++mi) {
            int row = wm + mi * 16 + l15;
            a[mi] = ld_frag(&Ab[row * 32 + (k8 ^ (row & 3)) * 8]);
        }
        for (int ni = 0; ni < 4; ++ni) {
            int row = wn + ni * 16 + l15;
            b[ni] = ld_frag(&Bb[row * 32 + (k8 ^ (row & 3)) * 8]);
        }
        WAIT_LG0;
        for (int mi = 0; mi < 8; ++mi)
            for (int ni = 0; ni < 4; ++ni)
                acc[mi][ni] = __builtin_amdgcn_mfma_f32_16x16x32_bf16(a[mi], b[ni], acc[mi][ni], 0, 0, 0);
        BARRIER;                 // reads of cur done before T(kt+3) overwrites it
        char* tmp = cur; cur = nx1; nx1 = nx2; nx2 = tmp;
    }

    // bf16 partial-sum store
    for (int mi = 0; mi < 8; ++mi)
        for (int ni = 0; ni < 4; ++ni)
            for (int r = 0; r < 4; ++r) {
                int row = wm + mi * 16 + k8 * 4 + r;
                int cm = m0 + row;
                int d = wn + ni * 16 + l15;
                if (cm < CH) part[((size_t)ks * CH + cm) * 256 + d] = f2b(acc[mi][ni][r]);
            }
}

// ---------------- REDUCE: out = query + bo + sum_ks part (bf16 part) ---------------
__global__ __launch_bounds__(256) void k_reduce(
    const unsigned short* __restrict__ part, const float* __restrict__ query,
    const float* __restrict__ bo, float* __restrict__ out, int q0, int CH)
{
    int row = blockIdx.x * 4 + (threadIdx.x >> 6);
    if (row >= CH) return;
    int d4 = (threadIdx.x & 63) * 4;
    f32x4 s = *(const f32x4*)&bo[d4];
    f32x4 qv = *(const f32x4*)&query[(size_t)(q0 + row) * 256 + d4];
    s = s + qv;
    for (int ks = 0; ks < KS2; ++ks) {
        u16x4 p4 = *(const u16x4*)&part[((size_t)ks * CH + row) * 256 + d4];
        s[0] += b2f(p4[0]); s[1] += b2f(p4[1]); s[2] += b2f(p4[2]); s[3] += b2f(p4[3]);
    }
    *(f32x4*)&out[(size_t)(q0 + row) * 256 + d4] = s;
}

extern "C" void kernel_launch(void* const* d_in, const int* in_sizes, int n_in,
                              void* d_out, int out_size, void* d_ws, size_t ws_size,
                              hipStream_t stream) {
    const float* x     = (const float*)d_in[0];
    const float* query = (const float*)d_in[1];
    const float* Wp    = (const float*)d_in[2];
    const float* bp    = (const float*)d_in[3];
    const float* Wo    = (const float*)d_in[4];
    const float* bo    = (const float*)d_in[5];
    float* out = (float*)d_out;

    char* ws = (char*)d_ws;
    unsigned short* Wpb = (unsigned short*)ws;                     // 16,777,216 B
    unsigned short* Wob = (unsigned short*)(ws + 16777216);        // 16,777,216 B
    unsigned short* qb  = (unsigned short*)(ws + 33554432);        //  2,048,000 B
    float*          bpp = (float*)(ws + 35602432);                 //    131,072 B
    char* chunkbase = ws + 35733504;
    const size_t fixed = 35733504;

    // CH=2000 (best-known config). part is bf16: KS2*CH*256*2 bytes.
    static const int cands[] = {2000, 1000, 500, 250, 200, 125, 100, 50, 25, 20, 10, 8, 5, 4, 2, 1};
    int CH = 1;
    for (int i = 0; i < (int)(sizeof(cands) / sizeof(cands[0])); ++i) {
        size_t need = fixed + (size_t)cands[i] * (65536 + (size_t)KS2 * 512);
        if (need <= ws_size) { CH = cands[i]; break; }
    }
    unsigned short* pm = (unsigned short*)chunkbase;
    unsigned short* part = (unsigned short*)(chunkbase + (size_t)CH * 65536);
    const int NC = 4000 / CH;

    k_perm_bp<<<128, 256, 0, stream>>>(bp, bpp);
    k_cvt_wp<<<2048, 256, 0, stream>>>(Wp, Wpb, 32768 * 256 / 4);
    k_cvt<<<2048, 256, 0, stream>>>(Wo, Wob, 256 * 32768 / 4);
    k_cvt<<<1000, 256, 0, stream>>>(query, qb, 4000 * 256 / 4);

    for (int c = 0; c < NC; ++c) {
        int q0 = c * CH;
        const int MB2 = (CH + 255) / 256;
        k_gemm1<<<dim3(256, (CH + 255) / 256), 512, 0, stream>>>(
            qb + (size_t)q0 * 256, Wpb, bpp, pm, CH);
        k_mix<<<dim3(4, CH), 256, 0, stream>>>(x, pm, q0);
        k_gemm2<<<dim3(KS2 * MB2), 512, 0, stream>>>(pm, Wob, part, CH, MB2);
        k_reduce<<<dim3((CH + 3) / 4), 256, 0, stream>>>(part, query, bo, out, q0, CH);
    }
}

// Round 14
// 349.120 us; speedup vs baseline: 1.0118x; 1.0118x over previous
//
#include <hip/hip_runtime.h>

typedef __attribute__((ext_vector_type(8))) __bf16 bf16x8;
typedef __attribute__((ext_vector_type(4))) float f32x4;
typedef __attribute__((ext_vector_type(8))) unsigned short u16x8;
typedef __attribute__((ext_vector_type(4))) unsigned short u16x4;
typedef unsigned int u32;

#define KS2 32   // gemm2 split-K factor; pm/Wob stored slice-major: [ks][rows][1024]

// f32 -> bf16 bits, round-to-nearest-even
__device__ __forceinline__ unsigned short f2b(float f) {
    union { float f; unsigned u; } v; v.f = f;
    unsigned r = v.u + 0x7fffu + ((v.u >> 16) & 1u);
    return (unsigned short)(r >> 16);
}

// bf16 bits -> f32
__device__ __forceinline__ float b2f(unsigned short b) {
    union { unsigned u; float f; } v; v.u = ((unsigned)b) << 16;
    return v.f;
}

__device__ __forceinline__ bf16x8 ld_frag(const unsigned short* p) {
    u16x8 v = *(const u16x8*)p;
    return __builtin_bit_cast(bf16x8, v);
}

// async 16B global -> LDS (linear dest: wave base + lane*16)
__device__ __forceinline__ void gl16(void* lds, const void* g) {
    __builtin_amdgcn_global_load_lds(
        (const __attribute__((address_space(1))) u32*)g,
        (__attribute__((address_space(3))) u32*)lds, 16, 0, 0);
}

#define WAIT_VM0 asm volatile("s_waitcnt vmcnt(0)" ::: "memory")
#define WAIT_VM3 asm volatile("s_waitcnt vmcnt(3)" ::: "memory")
#define WAIT_VM6 asm volatile("s_waitcnt vmcnt(6)" ::: "memory")
#define WAIT_LG0 asm volatile("s_waitcnt lgkmcnt(0)" ::: "memory")
#define BARRIER  __builtin_amdgcn_s_barrier()

// params-column permutation: pm col j holds original param index inv(j)
__device__ __forceinline__ int inv_col(int j) {
    int off = j & 8191;
    return (off < 4096) ? ((j & ~8191) | ((off & 63) << 6) | (off >> 6)) : j;
}

// block-wide sum of s and q across 256 threads (4 waves), deterministic
__device__ __forceinline__ void block_reduce2(float& s, float& q, float* red) {
    for (int m = 1; m < 64; m <<= 1) { s += __shfl_xor(s, m); q += __shfl_xor(q, m); }
    int w = threadIdx.x >> 6;
    __syncthreads();
    if ((threadIdx.x & 63) == 0) { red[w] = s; red[w + 4] = q; }
    __syncthreads();
    s = red[0] + red[1] + red[2] + red[3];
    q = red[4] + red[5] + red[6] + red[7];
}

// ---------------- conversion kernels -----------------------------------------------
__global__ __launch_bounds__(256) void k_cvt(const float* __restrict__ src,
                                             unsigned short* __restrict__ dst, int n4) {
    int i = blockIdx.x * 256 + threadIdx.x;
    int stride = gridDim.x * 256;
    for (; i < n4; i += stride) {
        f32x4 v = *(const f32x4*)&src[(size_t)i * 4];
        u16x4 o = { f2b(v[0]), f2b(v[1]), f2b(v[2]), f2b(v[3]) };
        *(u16x4*)&dst[(size_t)i * 4] = o;
    }
}

__global__ __launch_bounds__(256) void k_cvt_wp(const float* __restrict__ Wp,
                                                unsigned short* __restrict__ Wpb, int n4) {
    int i = blockIdx.x * 256 + threadIdx.x;
    int stride = gridDim.x * 256;
    for (; i < n4; i += stride) {
        int e = i * 4;
        int j = e >> 8, k = e & 255;
        int jo = inv_col(j);
        f32x4 v = *(const f32x4*)&Wp[(size_t)jo * 256 + k];
        u16x4 o = { f2b(v[0]), f2b(v[1]), f2b(v[2]), f2b(v[3]) };
        *(u16x4*)&Wpb[(size_t)e] = o;
    }
}

// Wo f32[256][32768] -> Wob bf16 slice-major [ks][256][1024]
__global__ __launch_bounds__(256) void k_cvt_wo(const float* __restrict__ Wo,
                                                unsigned short* __restrict__ Wob, int n4) {
    int i = blockIdx.x * 256 + threadIdx.x;
    int stride = gridDim.x * 256;
    for (; i < n4; i += stride) {
        int e = i * 4;
        int off = e & 1023;
        int rowidx = e >> 10;
        int d = rowidx & 255;
        int ks = rowidx >> 8;
        f32x4 v = *(const f32x4*)&Wo[(size_t)d * 32768 + ks * 1024 + off];
        u16x4 o = { f2b(v[0]), f2b(v[1]), f2b(v[2]), f2b(v[3]) };
        *(u16x4*)&Wob[(size_t)e] = o;
    }
}

__global__ __launch_bounds__(256) void k_perm_bp(const float* __restrict__ bp,
                                                 float* __restrict__ bpp) {
    int j = blockIdx.x * 256 + threadIdx.x;
    bpp[j] = bp[inv_col(j)];
}

// LDS slot swizzle: physical slot p of row r holds global slot p ^ (r & 3).

// ---------------- GEMM1: pm = qb @ Wpb^T + bpp (bf16, slice-major out) -------------
// BM=256, BN=128, BK=32, 8 waves (4m x 2n). 3-buffer 2-deep counted-vmcnt pipeline.
__global__ __launch_bounds__(512) void k_gemm1(
    const unsigned short* __restrict__ qb, const unsigned short* __restrict__ Wpb,
    const float* __restrict__ bpp, unsigned short* __restrict__ pm, int CH)
{
    __shared__ char SB[73728];   // 3 bufs x 24K; epilogue Ep (64K) aliases front
    const int t = threadIdx.x, lane = t & 63, w = t >> 6;
    const int l15 = lane & 15, k8 = lane >> 4;
    const int n0 = blockIdx.x * 128, m0 = blockIdx.y * 256;
    const int wm = (w >> 1) * 64, wn = (w & 1) * 64;

    f32x4 acc[4][4];
    for (int i = 0; i < 4; ++i)
        for (int j = 0; j < 4; ++j) acc[i][j] = (f32x4){0.f, 0.f, 0.f, 0.f};

    const int r0 = t >> 2;
    const int cbs = (((t & 3) ^ (r0 & 3)) * 16);   // swizzled source slot
    int ma0 = m0 + r0;        if (ma0 > CH - 1) ma0 = CH - 1;
    int ma1 = m0 + r0 + 128;  if (ma1 > CH - 1) ma1 = CH - 1;
    const char* pa0 = (const char*)qb  + (size_t)ma0 * 512 + cbs;
    const char* pa1 = (const char*)qb  + (size_t)ma1 * 512 + cbs;
    const char* pb0 = (const char*)Wpb + (size_t)(n0 + r0) * 512 + cbs;

    char* cur = SB;
    char* nx1 = SB + 24576;
    char* nx2 = SB + 49152;

    // prologue: issue T0, T1
    gl16(cur + t * 16,         pa0);
    gl16(cur + 8192 + t * 16,  pa1);
    gl16(cur + 16384 + t * 16, pb0);
    gl16(nx1 + t * 16,         pa0 + 64);
    gl16(nx1 + 8192 + t * 16,  pa1 + 64);
    gl16(nx1 + 16384 + t * 16, pb0 + 64);

    for (int kt = 0; kt < 8; ++kt) {
        if (kt < 6) {
            const int kb = (kt + 2) * 64;
            gl16(nx2 + t * 16,         pa0 + kb);
            gl16(nx2 + 8192 + t * 16,  pa1 + kb);
            gl16(nx2 + 16384 + t * 16, pb0 + kb);
            WAIT_VM6;            // T(kt)'s 3 loads retired; 6 in flight
        } else if (kt == 6) {
            WAIT_VM3;
        } else {
            WAIT_VM0;
        }
        BARRIER;
        const unsigned short* Ab = (const unsigned short*)cur;
        const unsigned short* Bb = (const unsigned short*)(cur + 16384);
        bf16x8 a[4], b[4];
        for (int mi = 0; mi < 4; ++mi) {
            int row = wm + mi * 16 + l15;
            a[mi] = ld_frag(&Ab[row * 32 + (k8 ^ (row & 3)) * 8]);
        }
        for (int ni = 0; ni < 4; ++ni) {
            int row = wn + ni * 16 + l15;
            b[ni] = ld_frag(&Bb[row * 32 + (k8 ^ (row & 3)) * 8]);
        }
        WAIT_LG0;
        for (int mi = 0; mi < 4; ++mi)
            for (int ni = 0; ni < 4; ++ni)
                acc[mi][ni] = __builtin_amdgcn_mfma_f32_16x16x32_bf16(a[mi], b[ni], acc[mi][ni], 0, 0, 0);
        BARRIER;                 // reads of cur done before T(kt+3) overwrites it
        char* tmp = cur; cur = nx1; nx1 = nx2; nx2 = tmp;
    }

    // epilogue: bias + pack into Ep (aliases staging bufs; safe after final barrier)
    unsigned short* Ep = (unsigned short*)SB;
    for (int ni = 0; ni < 4; ++ni) {
        int col = wn + ni * 16 + l15;
        float bpv = bpp[n0 + col];
        for (int mi = 0; mi < 4; ++mi)
            for (int r = 0; r < 4; ++r) {
                int row = wm + mi * 16 + k8 * 4 + r;
                Ep[row * 128 + col] = f2b(acc[mi][ni][r] + bpv);
            }
    }
    __syncthreads();
    // slice-major store: pm[ks][cm][1024]; this block's 128 cols lie in slice n0>>10
    const int ksg = n0 >> 10;
    const int cb0 = (n0 & 1023) * 2;     // byte offset within 2048-B slice row
    for (int i = 0; i < 8; ++i) {
        int off = t * 16 + i * 8192;
        int row = off >> 8, colb = off & 255;
        int cm = m0 + row;
        if (cm < CH)
            *(u16x8*)((char*)pm + ((size_t)ksg * CH + cm) * 2048 + cb0 + colb) =
                *(const u16x8*)((const char*)SB + off);
    }
}

// ---------------- MIX: per (g, nq) block; in-place params->mid (slice-major pm) ----
__global__ __launch_bounds__(256) void k_mix(
    const float* __restrict__ x, unsigned short* __restrict__ pm, int q0, int CH)
{
    __shared__ char SB[29184];      // MtP | Ax | Ss | O1 ; O2 aliases front 16KB
    __shared__ float red[8];
    unsigned short* MtP = (unsigned short*)SB;             // [64][72]  M^T
    unsigned short* Ax  = (unsigned short*)(SB + 9216);    // [32][72]
    unsigned short* Ss  = (unsigned short*)(SB + 13824);   // [128][40]
    unsigned short* O1  = (unsigned short*)(SB + 24064);   // [64][40]  out1^T
    unsigned short* O2  = (unsigned short*)SB;             // [128][64] final, aliased
    const int t = threadIdx.x, lane = t & 63, w = t >> 6;
    const int l15 = lane & 15, k8 = lane >> 4;
    const int g = blockIdx.x, nq = blockIdx.y;
    // params elem j of (g,nq) lives at pm byte ((g*8 + (j>>10))*CH + nq)*2048 + (j&1023)*2
    char* pmb = (char*)pm;
    const size_t rowb = 2048;
    const float* xg = x + ((size_t)(q0 + nq) * 4 + g) * 2048;

    { // stage M^T (already transposed by Wp permutation): j = d*64 + c0
        int d = t >> 2, c0 = (t & 3) * 16;
        const char* src = pmb + ((size_t)(g * 8 + (d >> 4)) * CH + nq) * rowb
                              + ((d & 15) * 64 + c0) * 2;
        u16x8 v0 = *(const u16x8*)(src);
        u16x8 v1 = *(const u16x8*)(src + 16);
        *(u16x8*)&MtP[d * 72 + c0] = v0;
        *(u16x8*)&MtP[d * 72 + c0 + 8] = v1;
    }
    { // stage S: j = 4096 + o*32 + p0
        int o = t >> 1, p0 = (t & 1) * 16;
        const char* src = pmb + ((size_t)(g * 8 + 4 + (o >> 5)) * CH + nq) * rowb
                              + ((o & 31) * 32 + p0) * 2;
        u16x8 v0 = *(const u16x8*)(src);
        u16x8 v1 = *(const u16x8*)(src + 16);
        *(u16x8*)&Ss[o * 40 + p0] = v0;
        *(u16x8*)&Ss[o * 40 + p0 + 8] = v1;
    }
    { // stage x (f32 -> bf16)
        int p = t >> 3, c0 = (t & 7) * 8;
        f32x4 v0 = *(const f32x4*)&xg[p * 64 + c0];
        f32x4 v1 = *(const f32x4*)&xg[p * 64 + c0 + 4];
        u16x8 o8 = { f2b(v0[0]), f2b(v0[1]), f2b(v0[2]), f2b(v0[3]),
                     f2b(v1[0]), f2b(v1[1]), f2b(v1[2]), f2b(v1[3]) };
        *(u16x8*)&Ax[p * 72 + c0] = o8;
    }
    __syncthreads();

    // out1 = x @ M : 32x64, K=64. Wave w owns cols 16w..16w+15.
    f32x4 acc1[2] = { (f32x4){0.f,0.f,0.f,0.f}, (f32x4){0.f,0.f,0.f,0.f} };
    for (int kk = 0; kk < 2; ++kk) {
        bf16x8 b = ld_frag(&MtP[(16 * w + l15) * 72 + kk * 32 + k8 * 8]);
        for (int mi = 0; mi < 2; ++mi) {
            bf16x8 a = ld_frag(&Ax[(mi * 16 + l15) * 72 + kk * 32 + k8 * 8]);
            acc1[mi] = __builtin_amdgcn_mfma_f32_16x16x32_bf16(a, b, acc1[mi], 0, 0, 0);
        }
    }
    float s = 0.f, sq = 0.f;
    for (int mi = 0; mi < 2; ++mi)
        for (int r = 0; r < 4; ++r) { float v = acc1[mi][r]; s += v; sq += v * v; }
    block_reduce2(s, sq, red);
    float mean = s * (1.f / 2048.f);
    float inv = rsqrtf(sq * (1.f / 2048.f) - mean * mean + 1e-5f);
    for (int mi = 0; mi < 2; ++mi)
        for (int r = 0; r < 4; ++r) {
            float v = (acc1[mi][r] - mean) * inv; v = fmaxf(v, 0.f);
            int p = mi * 16 + k8 * 4 + r, d = 16 * w + l15;
            O1[d * 40 + p] = f2b(v);
        }
    __syncthreads();

    // out2 = S @ out1 : 128x64, K=32
    f32x4 acc2[8];
    for (int mi = 0; mi < 8; ++mi) acc2[mi] = (f32x4){0.f, 0.f, 0.f, 0.f};
    bf16x8 b2 = ld_frag(&O1[(16 * w + l15) * 40 + k8 * 8]);
    for (int mi = 0; mi < 8; ++mi) {
        bf16x8 a2 = ld_frag(&Ss[(mi * 16 + l15) * 40 + k8 * 8]);
        acc2[mi] = __builtin_amdgcn_mfma_f32_16x16x32_bf16(a2, b2, acc2[mi], 0, 0, 0);
    }
    s = 0.f; sq = 0.f;
    for (int mi = 0; mi < 8; ++mi)
        for (int r = 0; r < 4; ++r) { float v = acc2[mi][r]; s += v; sq += v * v; }
    block_reduce2(s, sq, red);   // contains barriers -> safe to alias O2 after
    mean = s * (1.f / 8192.f);
    inv = rsqrtf(sq * (1.f / 8192.f) - mean * mean + 1e-5f);
    for (int mi = 0; mi < 8; ++mi)
        for (int r = 0; r < 4; ++r) {
            float v = (acc2[mi][r] - mean) * inv; v = fmaxf(v, 0.f);
            int o = mi * 16 + k8 * 4 + r, d = 16 * w + l15;
            O2[o * 64 + d] = f2b(v);
        }
    __syncthreads();
    // write-back to slice-major pm: elem = off/2, slice = g*8 + (elem>>10)
    for (int i = 0; i < 4; ++i) {
        int off = t * 16 + i * 4096;
        int elem = off >> 1;
        char* dst = pmb + ((size_t)(g * 8 + (elem >> 10)) * CH + nq) * rowb
                        + (elem & 1023) * 2;
        *(u16x8*)dst = *(const u16x8*)((const char*)O2 + off);
    }
}

// ---------------- GEMM2: part[ks,CH,256] = pm @ Wob^T (slice-major, bf16 part) -----
// BM=128, BN=256 (full), BK=32, 8 waves (2m x 4n). 3-buffer 2-deep pipeline.
// Slice-major layouts: A-tile = contiguous 256 KB, B-tile = contiguous 512 KB.
__global__ __launch_bounds__(512) void k_gemm2(
    const unsigned short* __restrict__ pm, const unsigned short* __restrict__ Wob,
    unsigned short* __restrict__ part, int CH)
{
    __shared__ char SB[73728];   // 3 bufs x (A 8K | B 16K)
    const int t = threadIdx.x, lane = t & 63, w = t >> 6;
    const int l15 = lane & 15, k8 = lane >> 4;
    const int m0 = blockIdx.x * 128;   // m fastest -> same-ks blocks share Wob slice
    const int ks = blockIdx.y;
    const int wm = (w >> 2) * 64, wn = (w & 3) * 64;

    f32x4 acc[4][4];
    for (int i = 0; i < 4; ++i)
        for (int j = 0; j < 4; ++j) acc[i][j] = (f32x4){0.f, 0.f, 0.f, 0.f};

    const int r0 = t >> 2;
    const int cbs = (((t & 3) ^ (r0 & 3)) * 16);   // swizzled source slot
    int ma = m0 + r0; if (ma > CH - 1) ma = CH - 1;
    const char* pa  = (const char*)pm  + ((size_t)ks * CH + ma) * 2048 + cbs;
    const char* pb0 = (const char*)Wob + ((size_t)ks * 256 + r0) * 2048 + cbs;
    const char* pb1 = pb0 + (size_t)128 * 2048;

    char* cur = SB;
    char* nx1 = SB + 24576;
    char* nx2 = SB + 49152;

    // prologue: issue T0, T1
    gl16(cur + t * 16,          pa);
    gl16(cur + 8192 + t * 16,   pb0);
    gl16(cur + 16384 + t * 16,  pb1);
    gl16(nx1 + t * 16,          pa + 64);
    gl16(nx1 + 8192 + t * 16,   pb0 + 64);
    gl16(nx1 + 16384 + t * 16,  pb1 + 64);

    const int NT = 2048 / 64;   // 32 K-steps over the 2048-B slice row
    for (int kt = 0; kt < NT; ++kt) {
        if (kt < NT - 2) {
            const int kb = (kt + 2) * 64;
            gl16(nx2 + t * 16,         pa  + kb);
            gl16(nx2 + 8192 + t * 16,  pb0 + kb);
            gl16(nx2 + 16384 + t * 16, pb1 + kb);
            WAIT_VM6;            // T(kt)'s 3 loads retired; 6 in flight
        } else if (kt == NT - 2) {
            WAIT_VM3;
        } else {
            WAIT_VM0;
        }
        BARRIER;
        const unsigned short* Ab = (const unsigned short*)cur;
        const unsigned short* Bb = (const unsigned short*)(cur + 8192);
        bf16x8 a[4], b[4];
        for (int mi = 0; mi < 4; ++mi) {
            int row = wm + mi * 16 + l15;
            a[mi] = ld_frag(&Ab[row * 32 + (k8 ^ (row & 3)) * 8]);
        }
        for (int ni = 0; ni < 4; ++ni) {
            int row = wn + ni * 16 + l15;
            b[ni] = ld_frag(&Bb[row * 32 + (k8 ^ (row & 3)) * 8]);
        }
        WAIT_LG0;
        for (int mi = 0; mi < 4; ++mi)
            for (int ni = 0; ni < 4; ++ni)
                acc[mi][ni] = __builtin_amdgcn_mfma_f32_16x16x32_bf16(a[mi], b[ni], acc[mi][ni], 0, 0, 0);
        BARRIER;                 // reads of cur done before T(kt+3) overwrites it
        char* tmp = cur; cur = nx1; nx1 = nx2; nx2 = tmp;
    }

    // bf16 partial-sum store
    for (int mi = 0; mi < 4; ++mi)
        for (int ni = 0; ni < 4; ++ni)
            for (int r = 0; r < 4; ++r) {
                int row = wm + mi * 16 + k8 * 4 + r;
                int cm = m0 + row;
                int d = wn + ni * 16 + l15;
                if (cm < CH) part[((size_t)ks * CH + cm) * 256 + d] = f2b(acc[mi][ni][r]);
            }
}

// ---------------- REDUCE: out = query + bo + sum_ks part (bf16 part) ---------------
__global__ __launch_bounds__(256) void k_reduce(
    const unsigned short* __restrict__ part, const float* __restrict__ query,
    const float* __restrict__ bo, float* __restrict__ out, int q0, int CH)
{
    int row = blockIdx.x * 4 + (threadIdx.x >> 6);
    if (row >= CH) return;
    int d4 = (threadIdx.x & 63) * 4;
    f32x4 s = *(const f32x4*)&bo[d4];
    f32x4 qv = *(const f32x4*)&query[(size_t)(q0 + row) * 256 + d4];
    s = s + qv;
    for (int ks = 0; ks < KS2; ++ks) {
        u16x4 p4 = *(const u16x4*)&part[((size_t)ks * CH + row) * 256 + d4];
        s[0] += b2f(p4[0]); s[1] += b2f(p4[1]); s[2] += b2f(p4[2]); s[3] += b2f(p4[3]);
    }
    *(f32x4*)&out[(size_t)(q0 + row) * 256 + d4] = s;
}

extern "C" void kernel_launch(void* const* d_in, const int* in_sizes, int n_in,
                              void* d_out, int out_size, void* d_ws, size_t ws_size,
                              hipStream_t stream) {
    const float* x     = (const float*)d_in[0];
    const float* query = (const float*)d_in[1];
    const float* Wp    = (const float*)d_in[2];
    const float* bp    = (const float*)d_in[3];
    const float* Wo    = (const float*)d_in[4];
    const float* bo    = (const float*)d_in[5];
    float* out = (float*)d_out;

    char* ws = (char*)d_ws;
    unsigned short* Wpb = (unsigned short*)ws;                     // 16,777,216 B
    unsigned short* Wob = (unsigned short*)(ws + 16777216);        // 16,777,216 B
    unsigned short* qb  = (unsigned short*)(ws + 33554432);        //  2,048,000 B
    float*          bpp = (float*)(ws + 35602432);                 //    131,072 B
    char* chunkbase = ws + 35733504;
    const size_t fixed = 35733504;

    // CH=2000 (best-known config). part is bf16: KS2*CH*256*2 bytes.
    static const int cands[] = {2000, 1000, 500, 250, 200, 125, 100, 50, 25, 20, 10, 8, 5, 4, 2, 1};
    int CH = 1;
    for (int i = 0; i < (int)(sizeof(cands) / sizeof(cands[0])); ++i) {
        size_t need = fixed + (size_t)cands[i] * (65536 + (size_t)KS2 * 512);
        if (need <= ws_size) { CH = cands[i]; break; }
    }
    unsigned short* pm = (unsigned short*)chunkbase;
    unsigned short* part = (unsigned short*)(chunkbase + (size_t)CH * 65536);
    const int NC = 4000 / CH;

    k_perm_bp<<<128, 256, 0, stream>>>(bp, bpp);
    k_cvt_wp<<<2048, 256, 0, stream>>>(Wp, Wpb, 32768 * 256 / 4);
    k_cvt_wo<<<2048, 256, 0, stream>>>(Wo, Wob, 256 * 32768 / 4);
    k_cvt<<<1000, 256, 0, stream>>>(query, qb, 4000 * 256 / 4);

    for (int c = 0; c < NC; ++c) {
        int q0 = c * CH;
        k_gemm1<<<dim3(256, (CH + 255) / 256), 512, 0, stream>>>(
            qb + (size_t)q0 * 256, Wpb, bpp, pm, CH);
        k_mix<<<dim3(4, CH), 256, 0, stream>>>(x, pm, q0, CH);
        k_gemm2<<<dim3((CH + 127) / 128, KS2), 512, 0, stream>>>(pm, Wob, part, CH);
        k_reduce<<<dim3((CH + 3) / 4), 256, 0, stream>>>(part, query, bo, out, q0, CH);
    }
}

// Round 15
// 342.835 us; speedup vs baseline: 1.0304x; 1.0183x over previous
//
#include <hip/hip_runtime.h>

typedef __attribute__((ext_vector_type(8))) __bf16 bf16x8;
typedef __attribute__((ext_vector_type(4))) float f32x4;
typedef __attribute__((ext_vector_type(8))) unsigned short u16x8;
typedef __attribute__((ext_vector_type(4))) unsigned short u16x4;
typedef unsigned int u32;

#define KS2 32   // gemm2 split-K factor; pm/Wob stored slice-major: [ks][rows][1024]

// f32 -> bf16 bits, round-to-nearest-even
__device__ __forceinline__ unsigned short f2b(float f) {
    union { float f; unsigned u; } v; v.f = f;
    unsigned r = v.u + 0x7fffu + ((v.u >> 16) & 1u);
    return (unsigned short)(r >> 16);
}

// bf16 bits -> f32
__device__ __forceinline__ float b2f(unsigned short b) {
    union { unsigned u; float f; } v; v.u = ((unsigned)b) << 16;
    return v.f;
}

__device__ __forceinline__ bf16x8 ld_frag(const unsigned short* p) {
    u16x8 v = *(const u16x8*)p;
    return __builtin_bit_cast(bf16x8, v);
}

// async 16B global -> LDS (linear dest: wave base + lane*16)
__device__ __forceinline__ void gl16(void* lds, const void* g) {
    __builtin_amdgcn_global_load_lds(
        (const __attribute__((address_space(1))) u32*)g,
        (__attribute__((address_space(3))) u32*)lds, 16, 0, 0);
}

#define WAIT_VM0 asm volatile("s_waitcnt vmcnt(0)" ::: "memory")
#define WAIT_VM3 asm volatile("s_waitcnt vmcnt(3)" ::: "memory")
#define WAIT_VM6 asm volatile("s_waitcnt vmcnt(6)" ::: "memory")
#define WAIT_LG0 asm volatile("s_waitcnt lgkmcnt(0)" ::: "memory")
#define BARRIER  __builtin_amdgcn_s_barrier()

// params-column permutation: pm col j holds original param index inv(j)
__device__ __forceinline__ int inv_col(int j) {
    int off = j & 8191;
    return (off < 4096) ? ((j & ~8191) | ((off & 63) << 6) | (off >> 6)) : j;
}

// block-wide sum of s and q across 256 threads (4 waves), deterministic
__device__ __forceinline__ void block_reduce2(float& s, float& q, float* red) {
    for (int m = 1; m < 64; m <<= 1) { s += __shfl_xor(s, m); q += __shfl_xor(q, m); }
    int w = threadIdx.x >> 6;
    __syncthreads();
    if ((threadIdx.x & 63) == 0) { red[w] = s; red[w + 4] = q; }
    __syncthreads();
    s = red[0] + red[1] + red[2] + red[3];
    q = red[4] + red[5] + red[6] + red[7];
}

// ---------------- conversion kernels -----------------------------------------------
__global__ __launch_bounds__(256) void k_cvt(const float* __restrict__ src,
                                             unsigned short* __restrict__ dst, int n4) {
    int i = blockIdx.x * 256 + threadIdx.x;
    int stride = gridDim.x * 256;
    for (; i < n4; i += stride) {
        f32x4 v = *(const f32x4*)&src[(size_t)i * 4];
        u16x4 o = { f2b(v[0]), f2b(v[1]), f2b(v[2]), f2b(v[3]) };
        *(u16x4*)&dst[(size_t)i * 4] = o;
    }
}

__global__ __launch_bounds__(256) void k_cvt_wp(const float* __restrict__ Wp,
                                                unsigned short* __restrict__ Wpb, int n4) {
    int i = blockIdx.x * 256 + threadIdx.x;
    int stride = gridDim.x * 256;
    for (; i < n4; i += stride) {
        int e = i * 4;
        int j = e >> 8, k = e & 255;
        int jo = inv_col(j);
        f32x4 v = *(const f32x4*)&Wp[(size_t)jo * 256 + k];
        u16x4 o = { f2b(v[0]), f2b(v[1]), f2b(v[2]), f2b(v[3]) };
        *(u16x4*)&Wpb[(size_t)e] = o;
    }
}

// Wo f32[256][32768] -> Wob bf16 slice-major [ks][256][1024]
__global__ __launch_bounds__(256) void k_cvt_wo(const float* __restrict__ Wo,
                                                unsigned short* __restrict__ Wob, int n4) {
    int i = blockIdx.x * 256 + threadIdx.x;
    int stride = gridDim.x * 256;
    for (; i < n4; i += stride) {
        int e = i * 4;
        int off = e & 1023;
        int rowidx = e >> 10;
        int d = rowidx & 255;
        int ks = rowidx >> 8;
        f32x4 v = *(const f32x4*)&Wo[(size_t)d * 32768 + ks * 1024 + off];
        u16x4 o = { f2b(v[0]), f2b(v[1]), f2b(v[2]), f2b(v[3]) };
        *(u16x4*)&Wob[(size_t)e] = o;
    }
}

__global__ __launch_bounds__(256) void k_perm_bp(const float* __restrict__ bp,
                                                 float* __restrict__ bpp) {
    int j = blockIdx.x * 256 + threadIdx.x;
    bpp[j] = bp[inv_col(j)];
}

// LDS slot swizzle: physical slot p of row r holds global slot p ^ (r & 3).

// ---------------- GEMM1: pm = qb @ Wpb^T + bpp (bf16, slice-major out) -------------
// BM=256, BN=128, BK=32, 8 waves (4m x 2n). 3-buffer 2-deep counted-vmcnt pipeline.
__global__ __launch_bounds__(512) void k_gemm1(
    const unsigned short* __restrict__ qb, const unsigned short* __restrict__ Wpb,
    const float* __restrict__ bpp, unsigned short* __restrict__ pm, int CH)
{
    __shared__ char SB[73728];   // 3 bufs x 24K; epilogue Ep (64K) aliases front
    const int t = threadIdx.x, lane = t & 63, w = t >> 6;
    const int l15 = lane & 15, k8 = lane >> 4;
    const int n0 = blockIdx.x * 128, m0 = blockIdx.y * 256;
    const int wm = (w >> 1) * 64, wn = (w & 1) * 64;

    f32x4 acc[4][4];
    for (int i = 0; i < 4; ++i)
        for (int j = 0; j < 4; ++j) acc[i][j] = (f32x4){0.f, 0.f, 0.f, 0.f};

    const int r0 = t >> 2;
    const int cbs = (((t & 3) ^ (r0 & 3)) * 16);   // swizzled source slot
    int ma0 = m0 + r0;        if (ma0 > CH - 1) ma0 = CH - 1;
    int ma1 = m0 + r0 + 128;  if (ma1 > CH - 1) ma1 = CH - 1;
    const char* pa0 = (const char*)qb  + (size_t)ma0 * 512 + cbs;
    const char* pa1 = (const char*)qb  + (size_t)ma1 * 512 + cbs;
    const char* pb0 = (const char*)Wpb + (size_t)(n0 + r0) * 512 + cbs;

    char* cur = SB;
    char* nx1 = SB + 24576;
    char* nx2 = SB + 49152;

    // prologue: issue T0, T1
    gl16(cur + t * 16,         pa0);
    gl16(cur + 8192 + t * 16,  pa1);
    gl16(cur + 16384 + t * 16, pb0);
    gl16(nx1 + t * 16,         pa0 + 64);
    gl16(nx1 + 8192 + t * 16,  pa1 + 64);
    gl16(nx1 + 16384 + t * 16, pb0 + 64);

    for (int kt = 0; kt < 8; ++kt) {
        if (kt < 6) {
            const int kb = (kt + 2) * 64;
            gl16(nx2 + t * 16,         pa0 + kb);
            gl16(nx2 + 8192 + t * 16,  pa1 + kb);
            gl16(nx2 + 16384 + t * 16, pb0 + kb);
            WAIT_VM6;            // T(kt)'s 3 loads retired; 6 in flight
        } else if (kt == 6) {
            WAIT_VM3;
        } else {
            WAIT_VM0;
        }
        BARRIER;
        const unsigned short* Ab = (const unsigned short*)cur;
        const unsigned short* Bb = (const unsigned short*)(cur + 16384);
        bf16x8 a[4], b[4];
        for (int mi = 0; mi < 4; ++mi) {
            int row = wm + mi * 16 + l15;
            a[mi] = ld_frag(&Ab[row * 32 + (k8 ^ (row & 3)) * 8]);
        }
        for (int ni = 0; ni < 4; ++ni) {
            int row = wn + ni * 16 + l15;
            b[ni] = ld_frag(&Bb[row * 32 + (k8 ^ (row & 3)) * 8]);
        }
        WAIT_LG0;
        for (int mi = 0; mi < 4; ++mi)
            for (int ni = 0; ni < 4; ++ni)
                acc[mi][ni] = __builtin_amdgcn_mfma_f32_16x16x32_bf16(a[mi], b[ni], acc[mi][ni], 0, 0, 0);
        BARRIER;                 // reads of cur done before T(kt+3) overwrites it
        char* tmp = cur; cur = nx1; nx1 = nx2; nx2 = tmp;
    }

    // epilogue: bias + pack into Ep (aliases staging bufs; safe after final barrier)
    unsigned short* Ep = (unsigned short*)SB;
    for (int ni = 0; ni < 4; ++ni) {
        int col = wn + ni * 16 + l15;
        float bpv = bpp[n0 + col];
        for (int mi = 0; mi < 4; ++mi)
            for (int r = 0; r < 4; ++r) {
                int row = wm + mi * 16 + k8 * 4 + r;
                Ep[row * 128 + col] = f2b(acc[mi][ni][r] + bpv);
            }
    }
    __syncthreads();
    // slice-major store: pm[ks][cm][1024]; this block's 128 cols lie in slice n0>>10
    const int ksg = n0 >> 10;
    const int cb0 = (n0 & 1023) * 2;     // byte offset within 2048-B slice row
    for (int i = 0; i < 8; ++i) {
        int off = t * 16 + i * 8192;
        int row = off >> 8, colb = off & 255;
        int cm = m0 + row;
        if (cm < CH)
            *(u16x8*)((char*)pm + ((size_t)ksg * CH + cm) * 2048 + cb0 + colb) =
                *(const u16x8*)((const char*)SB + off);
    }
}

// ---------------- MIX: per (g, nq) block; in-place params->mid (slice-major pm) ----
__global__ __launch_bounds__(256) void k_mix(
    const float* __restrict__ x, unsigned short* __restrict__ pm, int q0, int CH)
{
    __shared__ char SB[29184];      // MtP | Ax | Ss | O1 ; O2 aliases front 16KB
    __shared__ float red[8];
    unsigned short* MtP = (unsigned short*)SB;             // [64][72]  M^T
    unsigned short* Ax  = (unsigned short*)(SB + 9216);    // [32][72]
    unsigned short* Ss  = (unsigned short*)(SB + 13824);   // [128][40]
    unsigned short* O1  = (unsigned short*)(SB + 24064);   // [64][40]  out1^T
    unsigned short* O2  = (unsigned short*)SB;             // [128][64] final, aliased
    const int t = threadIdx.x, lane = t & 63, w = t >> 6;
    const int l15 = lane & 15, k8 = lane >> 4;
    const int g = blockIdx.x, nq = blockIdx.y;
    // params elem j of (g,nq) lives at pm byte ((g*8 + (j>>10))*CH + nq)*2048 + (j&1023)*2
    char* pmb = (char*)pm;
    const size_t rowb = 2048;
    const float* xg = x + ((size_t)(q0 + nq) * 4 + g) * 2048;

    { // stage M^T (already transposed by Wp permutation): j = d*64 + c0
        int d = t >> 2, c0 = (t & 3) * 16;
        const char* src = pmb + ((size_t)(g * 8 + (d >> 4)) * CH + nq) * rowb
                              + ((d & 15) * 64 + c0) * 2;
        u16x8 v0 = *(const u16x8*)(src);
        u16x8 v1 = *(const u16x8*)(src + 16);
        *(u16x8*)&MtP[d * 72 + c0] = v0;
        *(u16x8*)&MtP[d * 72 + c0 + 8] = v1;
    }
    { // stage S: j = 4096 + o*32 + p0
        int o = t >> 1, p0 = (t & 1) * 16;
        const char* src = pmb + ((size_t)(g * 8 + 4 + (o >> 5)) * CH + nq) * rowb
                              + ((o & 31) * 32 + p0) * 2;
        u16x8 v0 = *(const u16x8*)(src);
        u16x8 v1 = *(const u16x8*)(src + 16);
        *(u16x8*)&Ss[o * 40 + p0] = v0;
        *(u16x8*)&Ss[o * 40 + p0 + 8] = v1;
    }
    { // stage x (f32 -> bf16)
        int p = t >> 3, c0 = (t & 7) * 8;
        f32x4 v0 = *(const f32x4*)&xg[p * 64 + c0];
        f32x4 v1 = *(const f32x4*)&xg[p * 64 + c0 + 4];
        u16x8 o8 = { f2b(v0[0]), f2b(v0[1]), f2b(v0[2]), f2b(v0[3]),
                     f2b(v1[0]), f2b(v1[1]), f2b(v1[2]), f2b(v1[3]) };
        *(u16x8*)&Ax[p * 72 + c0] = o8;
    }
    __syncthreads();

    // out1 = x @ M : 32x64, K=64. Wave w owns cols 16w..16w+15.
    f32x4 acc1[2] = { (f32x4){0.f,0.f,0.f,0.f}, (f32x4){0.f,0.f,0.f,0.f} };
    for (int kk = 0; kk < 2; ++kk) {
        bf16x8 b = ld_frag(&MtP[(16 * w + l15) * 72 + kk * 32 + k8 * 8]);
        for (int mi = 0; mi < 2; ++mi) {
            bf16x8 a = ld_frag(&Ax[(mi * 16 + l15) * 72 + kk * 32 + k8 * 8]);
            acc1[mi] = __builtin_amdgcn_mfma_f32_16x16x32_bf16(a, b, acc1[mi], 0, 0, 0);
        }
    }
    float s = 0.f, sq = 0.f;
    for (int mi = 0; mi < 2; ++mi)
        for (int r = 0; r < 4; ++r) { float v = acc1[mi][r]; s += v; sq += v * v; }
    block_reduce2(s, sq, red);
    float mean = s * (1.f / 2048.f);
    float inv = rsqrtf(sq * (1.f / 2048.f) - mean * mean + 1e-5f);
    for (int mi = 0; mi < 2; ++mi)
        for (int r = 0; r < 4; ++r) {
            float v = (acc1[mi][r] - mean) * inv; v = fmaxf(v, 0.f);
            int p = mi * 16 + k8 * 4 + r, d = 16 * w + l15;
            O1[d * 40 + p] = f2b(v);
        }
    __syncthreads();

    // out2 = S @ out1 : 128x64, K=32
    f32x4 acc2[8];
    for (int mi = 0; mi < 8; ++mi) acc2[mi] = (f32x4){0.f, 0.f, 0.f, 0.f};
    bf16x8 b2 = ld_frag(&O1[(16 * w + l15) * 40 + k8 * 8]);
    for (int mi = 0; mi < 8; ++mi) {
        bf16x8 a2 = ld_frag(&Ss[(mi * 16 + l15) * 40 + k8 * 8]);
        acc2[mi] = __builtin_amdgcn_mfma_f32_16x16x32_bf16(a2, b2, acc2[mi], 0, 0, 0);
    }
    s = 0.f; sq = 0.f;
    for (int mi = 0; mi < 8; ++mi)
        for (int r = 0; r < 4; ++r) { float v = acc2[mi][r]; s += v; sq += v * v; }
    block_reduce2(s, sq, red);   // contains barriers -> safe to alias O2 after
    mean = s * (1.f / 8192.f);
    inv = rsqrtf(sq * (1.f / 8192.f) - mean * mean + 1e-5f);
    for (int mi = 0; mi < 8; ++mi)
        for (int r = 0; r < 4; ++r) {
            float v = (acc2[mi][r] - mean) * inv; v = fmaxf(v, 0.f);
            int o = mi * 16 + k8 * 4 + r, d = 16 * w + l15;
            O2[o * 64 + d] = f2b(v);
        }
    __syncthreads();
    // write-back to slice-major pm: elem = off/2, slice = g*8 + (elem>>10)
    for (int i = 0; i < 4; ++i) {
        int off = t * 16 + i * 4096;
        int elem = off >> 1;
        char* dst = pmb + ((size_t)(g * 8 + (elem >> 10)) * CH + nq) * rowb
                        + (elem & 1023) * 2;
        *(u16x8*)dst = *(const u16x8*)((const char*)O2 + off);
    }
}

// ---------------- GEMM2: part[ks,CH,256] = pm @ Wob^T (slice-major, bf16 part) -----
// BM=128, BN=256 (full), BK=32, 8 waves (2m x 4n). 3-buffer 2-deep pipeline.
// ks->XCD swizzle (R8-validated on gemm2): all m-blocks of one ks pinned to one
// XCD -> its contiguous 512 KB Wob slice is L2-resident; re-reads are L2 hits.
__global__ __launch_bounds__(512) void k_gemm2(
    const unsigned short* __restrict__ pm, const unsigned short* __restrict__ Wob,
    unsigned short* __restrict__ part, int CH, int MB2)
{
    __shared__ char SB[73728];   // 3 bufs x (A 8K | B 16K)
    const int t = threadIdx.x, lane = t & 63, w = t >> 6;
    const int l15 = lane & 15, k8 = lane >> 4;
    // swizzle: grid = KS2*MB2 (multiple of 8). xcd = bid&7; same-ks -> same XCD.
    const int bid = blockIdx.x;
    const int xcd = bid & 7, local = bid >> 3;
    const int ks = xcd + 8 * (local / MB2);
    const int m0 = (local % MB2) * 128;
    const int wm = (w >> 2) * 64, wn = (w & 3) * 64;

    f32x4 acc[4][4];
    for (int i = 0; i < 4; ++i)
        for (int j = 0; j < 4; ++j) acc[i][j] = (f32x4){0.f, 0.f, 0.f, 0.f};

    const int r0 = t >> 2;
    const int cbs = (((t & 3) ^ (r0 & 3)) * 16);   // swizzled source slot
    int ma = m0 + r0; if (ma > CH - 1) ma = CH - 1;
    const char* pa  = (const char*)pm  + ((size_t)ks * CH + ma) * 2048 + cbs;
    const char* pb0 = (const char*)Wob + ((size_t)ks * 256 + r0) * 2048 + cbs;
    const char* pb1 = pb0 + (size_t)128 * 2048;

    char* cur = SB;
    char* nx1 = SB + 24576;
    char* nx2 = SB + 49152;

    // prologue: issue T0, T1
    gl16(cur + t * 16,          pa);
    gl16(cur + 8192 + t * 16,   pb0);
    gl16(cur + 16384 + t * 16,  pb1);
    gl16(nx1 + t * 16,          pa + 64);
    gl16(nx1 + 8192 + t * 16,   pb0 + 64);
    gl16(nx1 + 16384 + t * 16,  pb1 + 64);

    const int NT = 2048 / 64;   // 32 K-steps over the 2048-B slice row
    for (int kt = 0; kt < NT; ++kt) {
        if (kt < NT - 2) {
            const int kb = (kt + 2) * 64;
            gl16(nx2 + t * 16,         pa  + kb);
            gl16(nx2 + 8192 + t * 16,  pb0 + kb);
            gl16(nx2 + 16384 + t * 16, pb1 + kb);
            WAIT_VM6;            // T(kt)'s 3 loads retired; 6 in flight
        } else if (kt == NT - 2) {
            WAIT_VM3;
        } else {
            WAIT_VM0;
        }
        BARRIER;
        const unsigned short* Ab = (const unsigned short*)cur;
        const unsigned short* Bb = (const unsigned short*)(cur + 8192);
        bf16x8 a[4], b[4];
        for (int mi = 0; mi < 4; ++mi) {
            int row = wm + mi * 16 + l15;
            a[mi] = ld_frag(&Ab[row * 32 + (k8 ^ (row & 3)) * 8]);
        }
        for (int ni = 0; ni < 4; ++ni) {
            int row = wn + ni * 16 + l15;
            b[ni] = ld_frag(&Bb[row * 32 + (k8 ^ (row & 3)) * 8]);
        }
        WAIT_LG0;
        for (int mi = 0; mi < 4; ++mi)
            for (int ni = 0; ni < 4; ++ni)
                acc[mi][ni] = __builtin_amdgcn_mfma_f32_16x16x32_bf16(a[mi], b[ni], acc[mi][ni], 0, 0, 0);
        BARRIER;                 // reads of cur done before T(kt+3) overwrites it
        char* tmp = cur; cur = nx1; nx1 = nx2; nx2 = tmp;
    }

    // bf16 partial-sum store
    for (int mi = 0; mi < 4; ++mi)
        for (int ni = 0; ni < 4; ++ni)
            for (int r = 0; r < 4; ++r) {
                int row = wm + mi * 16 + k8 * 4 + r;
                int cm = m0 + row;
                int d = wn + ni * 16 + l15;
                if (cm < CH) part[((size_t)ks * CH + cm) * 256 + d] = f2b(acc[mi][ni][r]);
            }
}

// ---------------- REDUCE: out = query + bo + sum_ks part (bf16 part) ---------------
__global__ __launch_bounds__(256) void k_reduce(
    const unsigned short* __restrict__ part, const float* __restrict__ query,
    const float* __restrict__ bo, float* __restrict__ out, int q0, int CH)
{
    int row = blockIdx.x * 4 + (threadIdx.x >> 6);
    if (row >= CH) return;
    int d4 = (threadIdx.x & 63) * 4;
    f32x4 s = *(const f32x4*)&bo[d4];
    f32x4 qv = *(const f32x4*)&query[(size_t)(q0 + row) * 256 + d4];
    s = s + qv;
    for (int ks = 0; ks < KS2; ++ks) {
        u16x4 p4 = *(const u16x4*)&part[((size_t)ks * CH + row) * 256 + d4];
        s[0] += b2f(p4[0]); s[1] += b2f(p4[1]); s[2] += b2f(p4[2]); s[3] += b2f(p4[3]);
    }
    *(f32x4*)&out[(size_t)(q0 + row) * 256 + d4] = s;
}

extern "C" void kernel_launch(void* const* d_in, const int* in_sizes, int n_in,
                              void* d_out, int out_size, void* d_ws, size_t ws_size,
                              hipStream_t stream) {
    const float* x     = (const float*)d_in[0];
    const float* query = (const float*)d_in[1];
    const float* Wp    = (const float*)d_in[2];
    const float* bp    = (const float*)d_in[3];
    const float* Wo    = (const float*)d_in[4];
    const float* bo    = (const float*)d_in[5];
    float* out = (float*)d_out;

    char* ws = (char*)d_ws;
    unsigned short* Wpb = (unsigned short*)ws;                     // 16,777,216 B
    unsigned short* Wob = (unsigned short*)(ws + 16777216);        // 16,777,216 B
    unsigned short* qb  = (unsigned short*)(ws + 33554432);        //  2,048,000 B
    float*          bpp = (float*)(ws + 35602432);                 //    131,072 B
    char* chunkbase = ws + 35733504;
    const size_t fixed = 35733504;

    // CH=2000 (best-known config). part is bf16: KS2*CH*256*2 bytes.
    static const int cands[] = {2000, 1000, 500, 250, 200, 125, 100, 50, 25, 20, 10, 8, 5, 4, 2, 1};
    int CH = 1;
    for (int i = 0; i < (int)(sizeof(cands) / sizeof(cands[0])); ++i) {
        size_t need = fixed + (size_t)cands[i] * (65536 + (size_t)KS2 * 512);
        if (need <= ws_size) { CH = cands[i]; break; }
    }
    unsigned short* pm = (unsigned short*)chunkbase;
    unsigned short* part = (unsigned short*)(chunkbase + (size_t)CH * 65536);
    const int NC = 4000 / CH;

    k_perm_bp<<<128, 256, 0, stream>>>(bp, bpp);
    k_cvt_wp<<<2048, 256, 0, stream>>>(Wp, Wpb, 32768 * 256 / 4);
    k_cvt_wo<<<2048, 256, 0, stream>>>(Wo, Wob, 256 * 32768 / 4);
    k_cvt<<<1000, 256, 0, stream>>>(query, qb, 4000 * 256 / 4);

    for (int c = 0; c < NC; ++c) {
        int q0 = c * CH;
        const int MB2 = (CH + 127) / 128;
        k_gemm1<<<dim3(256, (CH + 255) / 256), 512, 0, stream>>>(
            qb + (size_t)q0 * 256, Wpb, bpp, pm, CH);
        k_mix<<<dim3(4, CH), 256, 0, stream>>>(x, pm, q0, CH);
        k_gemm2<<<dim3(KS2 * MB2), 512, 0, stream>>>(pm, Wob, part, CH, MB2);
        k_reduce<<<dim3((CH + 3) / 4), 256, 0, stream>>>(part, query, bo, out, q0, CH);
    }
}

// Round 17
// 338.943 us; speedup vs baseline: 1.0422x; 1.0115x over previous
//
#include <hip/hip_runtime.h>

typedef __attribute__((ext_vector_type(8))) __bf16 bf16x8;
typedef __attribute__((ext_vector_type(4))) float f32x4;
typedef __attribute__((ext_vector_type(8))) unsigned short u16x8;
typedef __attribute__((ext_vector_type(4))) unsigned short u16x4;
typedef unsigned int u32;

#define KS2 32   // gemm2 split-K factor; pm/Wob stored slice-major: [ks][rows][1024]

// f32 -> bf16 bits, round-to-nearest-even
__device__ __forceinline__ unsigned short f2b(float f) {
    union { float f; unsigned u; } v; v.f = f;
    unsigned r = v.u + 0x7fffu + ((v.u >> 16) & 1u);
    return (unsigned short)(r >> 16);
}

// bf16 bits -> f32
__device__ __forceinline__ float b2f(unsigned short b) {
    union { unsigned u; float f; } v; v.u = ((unsigned)b) << 16;
    return v.f;
}

__device__ __forceinline__ bf16x8 ld_frag(const unsigned short* p) {
    u16x8 v = *(const u16x8*)p;
    return __builtin_bit_cast(bf16x8, v);
}

// async 16B global -> LDS (linear dest: wave base + lane*16)
__device__ __forceinline__ void gl16(void* lds, const void* g) {
    __builtin_amdgcn_global_load_lds(
        (const __attribute__((address_space(1))) u32*)g,
        (__attribute__((address_space(3))) u32*)lds, 16, 0, 0);
}

#define WAIT_VM0 asm volatile("s_waitcnt vmcnt(0)" ::: "memory")
#define WAIT_VM3 asm volatile("s_waitcnt vmcnt(3)" ::: "memory")
#define WAIT_VM6 asm volatile("s_waitcnt vmcnt(6)" ::: "memory")
#define WAIT_LG0 asm volatile("s_waitcnt lgkmcnt(0)" ::: "memory")
#define BARRIER  __builtin_amdgcn_s_barrier()

// params-column permutation: pm col j holds original param index inv(j)
__device__ __forceinline__ int inv_col(int j) {
    int off = j & 8191;
    return (off < 4096) ? ((j & ~8191) | ((off & 63) << 6) | (off >> 6)) : j;
}

// block-wide sum of s and q across 256 threads (4 waves), deterministic
__device__ __forceinline__ void block_reduce2(float& s, float& q, float* red) {
    for (int m = 1; m < 64; m <<= 1) { s += __shfl_xor(s, m); q += __shfl_xor(q, m); }
    int w = threadIdx.x >> 6;
    __syncthreads();
    if ((threadIdx.x & 63) == 0) { red[w] = s; red[w + 4] = q; }
    __syncthreads();
    s = red[0] + red[1] + red[2] + red[3];
    q = red[4] + red[5] + red[6] + red[7];
}

// ---------------- conversion kernels -----------------------------------------------
__global__ __launch_bounds__(256) void k_cvt(const float* __restrict__ src,
                                             unsigned short* __restrict__ dst, int n4) {
    int i = blockIdx.x * 256 + threadIdx.x;
    int stride = gridDim.x * 256;
    for (; i < n4; i += stride) {
        f32x4 v = *(const f32x4*)&src[(size_t)i * 4];
        u16x4 o = { f2b(v[0]), f2b(v[1]), f2b(v[2]), f2b(v[3]) };
        *(u16x4*)&dst[(size_t)i * 4] = o;
    }
}

__global__ __launch_bounds__(256) void k_cvt_wp(const float* __restrict__ Wp,
                                                unsigned short* __restrict__ Wpb, int n4) {
    int i = blockIdx.x * 256 + threadIdx.x;
    int stride = gridDim.x * 256;
    for (; i < n4; i += stride) {
        int e = i * 4;
        int j = e >> 8, k = e & 255;
        int jo = inv_col(j);
        f32x4 v = *(const f32x4*)&Wp[(size_t)jo * 256 + k];
        u16x4 o = { f2b(v[0]), f2b(v[1]), f2b(v[2]), f2b(v[3]) };
        *(u16x4*)&Wpb[(size_t)e] = o;
    }
}

// Wo f32[256][32768] -> Wob bf16 slice-major [ks][256][1024]
__global__ __launch_bounds__(256) void k_cvt_wo(const float* __restrict__ Wo,
                                                unsigned short* __restrict__ Wob, int n4) {
    int i = blockIdx.x * 256 + threadIdx.x;
    int stride = gridDim.x * 256;
    for (; i < n4; i += stride) {
        int e = i * 4;
        int off = e & 1023;
        int rowidx = e >> 10;
        int d = rowidx & 255;
        int ks = rowidx >> 8;
        f32x4 v = *(const f32x4*)&Wo[(size_t)d * 32768 + ks * 1024 + off];
        u16x4 o = { f2b(v[0]), f2b(v[1]), f2b(v[2]), f2b(v[3]) };
        *(u16x4*)&Wob[(size_t)e] = o;
    }
}

__global__ __launch_bounds__(256) void k_perm_bp(const float* __restrict__ bp,
                                                 float* __restrict__ bpp) {
    int j = blockIdx.x * 256 + threadIdx.x;
    bpp[j] = bp[inv_col(j)];
}

// LDS slot swizzle: physical slot p of row r holds global slot p ^ (r & 3).

// ---------------- GEMM1: pm = qb @ Wpb^T + bpp (bf16, slice-major out) -------------
// BM=256, BN=128, BK=32, 8 waves (4m x 2n). 3-buffer 2-deep counted-vmcnt pipeline.
__global__ __launch_bounds__(512) void k_gemm1(
    const unsigned short* __restrict__ qb, const unsigned short* __restrict__ Wpb,
    const float* __restrict__ bpp, unsigned short* __restrict__ pm, int CH)
{
    __shared__ char SB[73728];   // 3 bufs x 24K; epilogue Ep (64K) aliases front
    const int t = threadIdx.x, lane = t & 63, w = t >> 6;
    const int l15 = lane & 15, k8 = lane >> 4;
    const int n0 = blockIdx.x * 128, m0 = blockIdx.y * 256;
    const int wm = (w >> 1) * 64, wn = (w & 1) * 64;

    f32x4 acc[4][4];
    for (int i = 0; i < 4; ++i)
        for (int j = 0; j < 4; ++j) acc[i][j] = (f32x4){0.f, 0.f, 0.f, 0.f};

    const int r0 = t >> 2;
    const int cbs = (((t & 3) ^ (r0 & 3)) * 16);   // swizzled source slot
    int ma0 = m0 + r0;        if (ma0 > CH - 1) ma0 = CH - 1;
    int ma1 = m0 + r0 + 128;  if (ma1 > CH - 1) ma1 = CH - 1;
    const char* pa0 = (const char*)qb  + (size_t)ma0 * 512 + cbs;
    const char* pa1 = (const char*)qb  + (size_t)ma1 * 512 + cbs;
    const char* pb0 = (const char*)Wpb + (size_t)(n0 + r0) * 512 + cbs;

    char* cur = SB;
    char* nx1 = SB + 24576;
    char* nx2 = SB + 49152;

    // prologue: issue T0, T1
    gl16(cur + t * 16,         pa0);
    gl16(cur + 8192 + t * 16,  pa1);
    gl16(cur + 16384 + t * 16, pb0);
    gl16(nx1 + t * 16,         pa0 + 64);
    gl16(nx1 + 8192 + t * 16,  pa1 + 64);
    gl16(nx1 + 16384 + t * 16, pb0 + 64);

    for (int kt = 0; kt < 8; ++kt) {
        if (kt < 6) {
            const int kb = (kt + 2) * 64;
            gl16(nx2 + t * 16,         pa0 + kb);
            gl16(nx2 + 8192 + t * 16,  pa1 + kb);
            gl16(nx2 + 16384 + t * 16, pb0 + kb);
            WAIT_VM6;            // T(kt)'s 3 loads retired; 6 in flight
        } else if (kt == 6) {
            WAIT_VM3;
        } else {
            WAIT_VM0;
        }
        BARRIER;
        const unsigned short* Ab = (const unsigned short*)cur;
        const unsigned short* Bb = (const unsigned short*)(cur + 16384);
        bf16x8 a[4], b[4];
        for (int mi = 0; mi < 4; ++mi) {
            int row = wm + mi * 16 + l15;
            a[mi] = ld_frag(&Ab[row * 32 + (k8 ^ (row & 3)) * 8]);
        }
        for (int ni = 0; ni < 4; ++ni) {
            int row = wn + ni * 16 + l15;
            b[ni] = ld_frag(&Bb[row * 32 + (k8 ^ (row & 3)) * 8]);
        }
        WAIT_LG0;
        for (int mi = 0; mi < 4; ++mi)
            for (int ni = 0; ni < 4; ++ni)
                acc[mi][ni] = __builtin_amdgcn_mfma_f32_16x16x32_bf16(a[mi], b[ni], acc[mi][ni], 0, 0, 0);
        BARRIER;                 // reads of cur done before T(kt+3) overwrites it
        char* tmp = cur; cur = nx1; nx1 = nx2; nx2 = tmp;
    }

    // epilogue: bias + pack into Ep (aliases staging bufs; safe after final barrier)
    unsigned short* Ep = (unsigned short*)SB;
    for (int ni = 0; ni < 4; ++ni) {
        int col = wn + ni * 16 + l15;
        float bpv = bpp[n0 + col];
        for (int mi = 0; mi < 4; ++mi)
            for (int r = 0; r < 4; ++r) {
                int row = wm + mi * 16 + k8 * 4 + r;
                Ep[row * 128 + col] = f2b(acc[mi][ni][r] + bpv);
            }
    }
    __syncthreads();
    // slice-major store: pm[ks][cm][1024]; this block's 128 cols lie in slice n0>>10
    const int ksg = n0 >> 10;
    const int cb0 = (n0 & 1023) * 2;     // byte offset within 2048-B slice row
    for (int i = 0; i < 8; ++i) {
        int off = t * 16 + i * 8192;
        int row = off >> 8, colb = off & 255;
        int cm = m0 + row;
        if (cm < CH)
            *(u16x8*)((char*)pm + ((size_t)ksg * CH + cm) * 2048 + cb0 + colb) =
                *(const u16x8*)((const char*)SB + off);
    }
}

// ---------------- MIX: per (g, nq) block; in-place params->mid (slice-major pm) ----
__global__ __launch_bounds__(256) void k_mix(
    const float* __restrict__ x, unsigned short* __restrict__ pm, int q0, int CH)
{
    __shared__ char SB[29184];      // MtP | Ax | Ss | O1 ; O2 aliases front 16KB
    __shared__ float red[8];
    unsigned short* MtP = (unsigned short*)SB;             // [64][72]  M^T
    unsigned short* Ax  = (unsigned short*)(SB + 9216);    // [32][72]
    unsigned short* Ss  = (unsigned short*)(SB + 13824);   // [128][40]
    unsigned short* O1  = (unsigned short*)(SB + 24064);   // [64][40]  out1^T
    unsigned short* O2  = (unsigned short*)SB;             // [128][64] final, aliased
    const int t = threadIdx.x, lane = t & 63, w = t >> 6;
    const int l15 = lane & 15, k8 = lane >> 4;
    const int g = blockIdx.x, nq = blockIdx.y;
    // params elem j of (g,nq) lives at pm byte ((g*8 + (j>>10))*CH + nq)*2048 + (j&1023)*2
    char* pmb = (char*)pm;
    const size_t rowb = 2048;
    const float* xg = x + ((size_t)(q0 + nq) * 4 + g) * 2048;

    { // stage M^T (already transposed by Wp permutation): j = d*64 + c0
        int d = t >> 2, c0 = (t & 3) * 16;
        const char* src = pmb + ((size_t)(g * 8 + (d >> 4)) * CH + nq) * rowb
                              + ((d & 15) * 64 + c0) * 2;
        u16x8 v0 = *(const u16x8*)(src);
        u16x8 v1 = *(const u16x8*)(src + 16);
        *(u16x8*)&MtP[d * 72 + c0] = v0;
        *(u16x8*)&MtP[d * 72 + c0 + 8] = v1;
    }
    { // stage S: j = 4096 + o*32 + p0
        int o = t >> 1, p0 = (t & 1) * 16;
        const char* src = pmb + ((size_t)(g * 8 + 4 + (o >> 5)) * CH + nq) * rowb
                              + ((o & 31) * 32 + p0) * 2;
        u16x8 v0 = *(const u16x8*)(src);
        u16x8 v1 = *(const u16x8*)(src + 16);
        *(u16x8*)&Ss[o * 40 + p0] = v0;
        *(u16x8*)&Ss[o * 40 + p0 + 8] = v1;
    }
    { // stage x (f32 -> bf16)
        int p = t >> 3, c0 = (t & 7) * 8;
        f32x4 v0 = *(const f32x4*)&xg[p * 64 + c0];
        f32x4 v1 = *(const f32x4*)&xg[p * 64 + c0 + 4];
        u16x8 o8 = { f2b(v0[0]), f2b(v0[1]), f2b(v0[2]), f2b(v0[3]),
                     f2b(v1[0]), f2b(v1[1]), f2b(v1[2]), f2b(v1[3]) };
        *(u16x8*)&Ax[p * 72 + c0] = o8;
    }
    __syncthreads();

    // out1 = x @ M : 32x64, K=64. Wave w owns cols 16w..16w+15.
    f32x4 acc1[2] = { (f32x4){0.f,0.f,0.f,0.f}, (f32x4){0.f,0.f,0.f,0.f} };
    for (int kk = 0; kk < 2; ++kk) {
        bf16x8 b = ld_frag(&MtP[(16 * w + l15) * 72 + kk * 32 + k8 * 8]);
        for (int mi = 0; mi < 2; ++mi) {
            bf16x8 a = ld_frag(&Ax[(mi * 16 + l15) * 72 + kk * 32 + k8 * 8]);
            acc1[mi] = __builtin_amdgcn_mfma_f32_16x16x32_bf16(a, b, acc1[mi], 0, 0, 0);
        }
    }
    float s = 0.f, sq = 0.f;
    for (int mi = 0; mi < 2; ++mi)
        for (int r = 0; r < 4; ++r) { float v = acc1[mi][r]; s += v; sq += v * v; }
    block_reduce2(s, sq, red);
    float mean = s * (1.f / 2048.f);
    float inv = rsqrtf(sq * (1.f / 2048.f) - mean * mean + 1e-5f);
    for (int mi = 0; mi < 2; ++mi)
        for (int r = 0; r < 4; ++r) {
            float v = (acc1[mi][r] - mean) * inv; v = fmaxf(v, 0.f);
            int p = mi * 16 + k8 * 4 + r, d = 16 * w + l15;
            O1[d * 40 + p] = f2b(v);
        }
    __syncthreads();

    // out2 = S @ out1 : 128x64, K=32
    f32x4 acc2[8];
    for (int mi = 0; mi < 8; ++mi) acc2[mi] = (f32x4){0.f, 0.f, 0.f, 0.f};
    bf16x8 b2 = ld_frag(&O1[(16 * w + l15) * 40 + k8 * 8]);
    for (int mi = 0; mi < 8; ++mi) {
        bf16x8 a2 = ld_frag(&Ss[(mi * 16 + l15) * 40 + k8 * 8]);
        acc2[mi] = __builtin_amdgcn_mfma_f32_16x16x32_bf16(a2, b2, acc2[mi], 0, 0, 0);
    }
    s = 0.f; sq = 0.f;
    for (int mi = 0; mi < 8; ++mi)
        for (int r = 0; r < 4; ++r) { float v = acc2[mi][r]; s += v; sq += v * v; }
    block_reduce2(s, sq, red);   // contains barriers -> safe to alias O2 after
    mean = s * (1.f / 8192.f);
    inv = rsqrtf(sq * (1.f / 8192.f) - mean * mean + 1e-5f);
    for (int mi = 0; mi < 8; ++mi)
        for (int r = 0; r < 4; ++r) {
            float v = (acc2[mi][r] - mean) * inv; v = fmaxf(v, 0.f);
            int o = mi * 16 + k8 * 4 + r, d = 16 * w + l15;
            O2[o * 64 + d] = f2b(v);
        }
    __syncthreads();
    // write-back to slice-major pm: elem = off/2, slice = g*8 + (elem>>10)
    for (int i = 0; i < 4; ++i) {
        int off = t * 16 + i * 4096;
        int elem = off >> 1;
        char* dst = pmb + ((size_t)(g * 8 + (elem >> 10)) * CH + nq) * rowb
                        + (elem & 1023) * 2;
        *(u16x8*)dst = *(const u16x8*)((const char*)O2 + off);
    }
}

// ---------------- GEMM2: part[ks,CH,256] = pm @ Wob^T (slice-major, bf16 part) -----
// BM=128, BN=256 (full), BK=32, 8 waves (2m x 4n). 3-buffer 2-deep pipeline.
// ks->XCD swizzle (R8/R15-validated): all m-blocks of one ks pinned to one XCD ->
// its contiguous 512 KB Wob slice is L2-resident; re-reads are L2 hits.
__global__ __launch_bounds__(512) void k_gemm2(
    const unsigned short* __restrict__ pm, const unsigned short* __restrict__ Wob,
    unsigned short* __restrict__ part, int CH, int MB2)
{
    __shared__ char SB[73728];   // 3 bufs x (A 8K | B 16K)
    const int t = threadIdx.x, lane = t & 63, w = t >> 6;
    const int l15 = lane & 15, k8 = lane >> 4;
    // swizzle: grid = KS2*MB2 (multiple of 8). xcd = bid&7; same-ks -> same XCD.
    const int bid = blockIdx.x;
    const int xcd = bid & 7, local = bid >> 3;
    const int ks = xcd + 8 * (local / MB2);
    const int m0 = (local % MB2) * 128;
    const int wm = (w >> 2) * 64, wn = (w & 3) * 64;

    f32x4 acc[4][4];
    for (int i = 0; i < 4; ++i)
        for (int j = 0; j < 4; ++j) acc[i][j] = (f32x4){0.f, 0.f, 0.f, 0.f};

    const int r0 = t >> 2;
    const int cbs = (((t & 3) ^ (r0 & 3)) * 16);   // swizzled source slot
    int ma = m0 + r0; if (ma > CH - 1) ma = CH - 1;
    const char* pa  = (const char*)pm  + ((size_t)ks * CH + ma) * 2048 + cbs;
    const char* pb0 = (const char*)Wob + ((size_t)ks * 256 + r0) * 2048 + cbs;
    const char* pb1 = pb0 + (size_t)128 * 2048;

    char* cur = SB;
    char* nx1 = SB + 24576;
    char* nx2 = SB + 49152;

    // prologue: issue T0, T1
    gl16(cur + t * 16,          pa);
    gl16(cur + 8192 + t * 16,   pb0);
    gl16(cur + 16384 + t * 16,  pb1);
    gl16(nx1 + t * 16,          pa + 64);
    gl16(nx1 + 8192 + t * 16,   pb0 + 64);
    gl16(nx1 + 16384 + t * 16,  pb1 + 64);

    const int NT = 2048 / 64;   // 32 K-steps over the 2048-B slice row
    for (int kt = 0; kt < NT; ++kt) {
        if (kt < NT - 2) {
            const int kb = (kt + 2) * 64;
            gl16(nx2 + t * 16,         pa  + kb);
            gl16(nx2 + 8192 + t * 16,  pb0 + kb);
            gl16(nx2 + 16384 + t * 16, pb1 + kb);
            WAIT_VM6;            // T(kt)'s 3 loads retired; 6 in flight
        } else if (kt == NT - 2) {
            WAIT_VM3;
        } else {
            WAIT_VM0;
        }
        BARRIER;
        const unsigned short* Ab = (const unsigned short*)cur;
        const unsigned short* Bb = (const unsigned short*)(cur + 8192);
        bf16x8 a[4], b[4];
        for (int mi = 0; mi < 4; ++mi) {
            int row = wm + mi * 16 + l15;
            a[mi] = ld_frag(&Ab[row * 32 + (k8 ^ (row & 3)) * 8]);
        }
        for (int ni = 0; ni < 4; ++ni) {
            int row = wn + ni * 16 + l15;
            b[ni] = ld_frag(&Bb[row * 32 + (k8 ^ (row & 3)) * 8]);
        }
        WAIT_LG0;
        for (int mi = 0; mi < 4; ++mi)
            for (int ni = 0; ni < 4; ++ni)
                acc[mi][ni] = __builtin_amdgcn_mfma_f32_16x16x32_bf16(a[mi], b[ni], acc[mi][ni], 0, 0, 0);
        BARRIER;                 // reads of cur done before T(kt+3) overwrites it
        char* tmp = cur; cur = nx1; nx1 = nx2; nx2 = tmp;
    }

    // bf16 partial-sum store
    for (int mi = 0; mi < 4; ++mi)
        for (int ni = 0; ni < 4; ++ni)
            for (int r = 0; r < 4; ++r) {
                int row = wm + mi * 16 + k8 * 4 + r;
                int cm = m0 + row;
                int d = wn + ni * 16 + l15;
                if (cm < CH) part[((size_t)ks * CH + cm) * 256 + d] = f2b(acc[mi][ni][r]);
            }
}

// ---------------- REDUCE: out = query + bo + sum_ks part (bf16 part) ---------------
__global__ __launch_bounds__(256) void k_reduce(
    const unsigned short* __restrict__ part, const float* __restrict__ query,
    const float* __restrict__ bo, float* __restrict__ out, int q0, int CH)
{
    int row = blockIdx.x * 4 + (threadIdx.x >> 6);
    if (row >= CH) return;
    int d4 = (threadIdx.x & 63) * 4;
    f32x4 s = *(const f32x4*)&bo[d4];
    f32x4 qv = *(const f32x4*)&query[(size_t)(q0 + row) * 256 + d4];
    s = s + qv;
    for (int ks = 0; ks < KS2; ++ks) {
        u16x4 p4 = *(const u16x4*)&part[((size_t)ks * CH + row) * 256 + d4];
        s[0] += b2f(p4[0]); s[1] += b2f(p4[1]); s[2] += b2f(p4[2]); s[3] += b2f(p4[3]);
    }
    *(f32x4*)&out[(size_t)(q0 + row) * 256 + d4] = s;
}

extern "C" void kernel_launch(void* const* d_in, const int* in_sizes, int n_in,
                              void* d_out, int out_size, void* d_ws, size_t ws_size,
                              hipStream_t stream) {
    const float* x     = (const float*)d_in[0];
    const float* query = (const float*)d_in[1];
    const float* Wp    = (const float*)d_in[2];
    const float* bp    = (const float*)d_in[3];
    const float* Wo    = (const float*)d_in[4];
    const float* bo    = (const float*)d_in[5];
    float* out = (float*)d_out;

    char* ws = (char*)d_ws;
    unsigned short* Wpb = (unsigned short*)ws;                     // 16,777,216 B
    unsigned short* Wob = (unsigned short*)(ws + 16777216);        // 16,777,216 B
    unsigned short* qb  = (unsigned short*)(ws + 33554432);        //  2,048,000 B
    float*          bpp = (float*)(ws + 35602432);                 //    131,072 B
    char* chunkbase = ws + 35733504;
    const size_t fixed = 35733504;

    // CH=2000 (best-known config). part is bf16: KS2*CH*256*2 bytes.
    static const int cands[] = {2000, 1000, 500, 250, 200, 125, 100, 50, 25, 20, 10, 8, 5, 4, 2, 1};
    int CH = 1;
    for (int i = 0; i < (int)(sizeof(cands) / sizeof(cands[0])); ++i) {
        size_t need = fixed + (size_t)cands[i] * (65536 + (size_t)KS2 * 512);
        if (need <= ws_size) { CH = cands[i]; break; }
    }
    unsigned short* pm = (unsigned short*)chunkbase;
    unsigned short* part = (unsigned short*)(chunkbase + (size_t)CH * 65536);
    const int NC = 4000 / CH;

    k_perm_bp<<<128, 256, 0, stream>>>(bp, bpp);
    k_cvt_wp<<<2048, 256, 0, stream>>>(Wp, Wpb, 32768 * 256 / 4);
    k_cvt_wo<<<2048, 256, 0, stream>>>(Wo, Wob, 256 * 32768 / 4);
    k_cvt<<<1000, 256, 0, stream>>>(query, qb, 4000 * 256 / 4);

    for (int c = 0; c < NC; ++c) {
        int q0 = c * CH;
        const int MB2 = (CH + 127) / 128;
        k_gemm1<<<dim3(256, (CH + 255) / 256), 512, 0, stream>>>(
            qb + (size_t)q0 * 256, Wpb, bpp, pm, CH);
        k_mix<<<dim3(4, CH), 256, 0, stream>>>(x, pm, q0, CH);
        k_gemm2<<<dim3(KS2 * MB2), 512, 0, stream>>>(pm, Wob, part, CH, MB2);
        k_reduce<<<dim3((CH + 3) / 4), 256, 0, stream>>>(part, query, bo, out, q0, CH);
    }
}